// Round 23
// baseline (128.057 us; speedup 1.0000x reference)
//
#include <hip/hip_runtime.h>
#include <hip/hip_bf16.h>
#include <stdint.h>

#define B_DIM 128
#define N_DIM 16384
#define E_DIM 1048576
#define H_DIM 512
#define C_DIM 10
#define NWG 256               // wgs for hist/place
#define CHUNK (E_DIM / NWG)   // 4096 edges per wg
#define NWORD8 (N_DIM / 4)    // 4096 words, 4 x 8-bit bins each
#define NGRP 8                // scan groups
#define WPG (NWG / NGRP)      // 32 wgs per group
#define SPLITK 64
#define KC (N_DIM / SPLITK)   // 256

typedef __attribute__((ext_vector_type(8))) short short8;   // 8 bf16 = 4 VGPRs
typedef __attribute__((ext_vector_type(4))) float f32x4;    // MFMA accumulator

// float -> bf16 round-to-nearest-even (finite inputs)
__device__ __forceinline__ uint32_t f2bf(float f) {
    uint32_t u = __float_as_uint(f);
    return (u + 0x7fffu + ((u >> 16) & 1u)) >> 16;
}

// ---------- 8-bit LDS histogram of dst (int4-vectorized loads) ----------
__global__ void __launch_bounds__(256) k_hist1(const int* __restrict__ dst,
                                               uint32_t* __restrict__ slab) {
    __shared__ uint32_t ls[NWORD8];   // 16 KB
    int bid = blockIdx.x, t = threadIdx.x;
#pragma unroll
    for (int i = 0; i < NWORD8 / 256; i++) ls[i * 256 + t] = 0;
    __syncthreads();
#pragma unroll
    for (int i = 0; i < CHUNK / 1024; i++) {   // 4 iters x 4 edges
        int4 d4 = *(const int4*)&dst[bid * CHUNK + i * 1024 + t * 4];
        atomicAdd(&ls[d4.x >> 2], 1u << ((d4.x & 3) << 3));
        atomicAdd(&ls[d4.y >> 2], 1u << ((d4.y & 3) << 3));
        atomicAdd(&ls[d4.z >> 2], 1u << ((d4.z & 3) << 3));
        atomicAdd(&ls[d4.w >> 2], 1u << ((d4.w & 3) << 3));
    }
    __syncthreads();
#pragma unroll
    for (int i = 0; i < NWORD8 / 256; i++)
        slab[(size_t)bid * NWORD8 + i * 256 + t] = ls[i * 256 + t];
}

// ---------- within-group (32 wgs) in-place exclusive prefix (SWAR 4x8-bit) ----
__global__ void __launch_bounds__(128) k_scanA8(uint32_t* __restrict__ slab,
                                                uint32_t* __restrict__ grp) {
    int b = blockIdx.x;                    // 0..255
    int g = b >> 5;                        // group 0..7
    int j = (b & 31) * 128 + threadIdx.x;  // word 0..4095
    uint32_t run = 0;                      // 4 byte-fields, each stays < 256
    for (int w = g * WPG; w < (g + 1) * WPG; w++) {
        uint32_t c = slab[(size_t)w * NWORD8 + j];
        slab[(size_t)w * NWORD8 + j] = run;
        run += c;                          // bytewise-safe (no field overflow)
    }
    grp[(size_t)g * NWORD8 + j] = run;
}

// ---------- cross-group prefix (in-place) + global bin scan -> CSR offs ----------
__global__ void __launch_bounds__(1024) k_scanBC8(uint32_t* __restrict__ grp,
                                                  int* __restrict__ offs) {
    __shared__ uint32_t part[1024];
    int t = threadIdx.x;
    uint32_t tw[4];
    int loc[16];
    uint32_t s = 0;
    int k = 0;
#pragma unroll
    for (int i = 0; i < 4; i++) {
        int j = t * 4 + i;
        uint32_t run = 0;
#pragma unroll
        for (int g = 0; g < NGRP; g++) {
            uint32_t c = grp[(size_t)g * NWORD8 + j];
            grp[(size_t)g * NWORD8 + j] = run;
            run += c;                      // bytewise-safe (totals < 256)
        }
        tw[i] = run;
#pragma unroll
        for (int b4 = 0; b4 < 4; b4++) {
            loc[k] = (int)s;
            s += (tw[i] >> (b4 * 8)) & 0xffu;
            k++;
        }
    }
    part[t] = s;
    __syncthreads();
    for (int off = 1; off < 1024; off <<= 1) {
        uint32_t v = (t >= off) ? part[t - off] : 0;
        __syncthreads();
        part[t] += v;
        __syncthreads();
    }
    uint32_t ex = (t == 0) ? 0 : part[t - 1];
#pragma unroll
    for (int i = 0; i < 16; i++) offs[t * 16 + i] = (int)(ex + loc[i]);
    if (t == 1023) offs[N_DIM] = (int)part[1023];
}

// ---------- atomic-free (global) placement: LDS cursor per wg ----------
// int4-vectorized edge loads; non-temporal 8B packed stores (write-once stream,
// avoids cross-XCD dirty-line traffic).
__global__ void __launch_bounds__(256) k_place2(const int* __restrict__ src,
                                                const int* __restrict__ dst,
                                                const float* __restrict__ ew,
                                                const uint32_t* __restrict__ slab,
                                                const uint32_t* __restrict__ grp,
                                                const int* __restrict__ offs,
                                                int2* __restrict__ packed) {
    __shared__ uint32_t cur[N_DIM];   // 64 KB
    int w = blockIdx.x, t = threadIdx.x;
    int g = w >> 5;
#pragma unroll
    for (int i = 0; i < NWORD8 / 256; i++) {
        int j = i * 256 + t;
        uint32_t pv = slab[(size_t)w * NWORD8 + j];
        uint32_t gv = grp[(size_t)g * NWORD8 + j];
        int4 o = *(const int4*)&offs[4 * j];
        cur[4 * j + 0] = (uint32_t)o.x + (gv & 0xffu) + (pv & 0xffu);
        cur[4 * j + 1] = (uint32_t)o.y + ((gv >> 8) & 0xffu) + ((pv >> 8) & 0xffu);
        cur[4 * j + 2] = (uint32_t)o.z + ((gv >> 16) & 0xffu) + ((pv >> 16) & 0xffu);
        cur[4 * j + 3] = (uint32_t)o.w + (gv >> 24) + (pv >> 24);
    }
    __syncthreads();
#pragma unroll
    for (int i = 0; i < CHUNK / 1024; i++) {   // 4 iters x 4 edges, 16B loads
        int e = w * CHUNK + i * 1024 + t * 4;
        int4 s4 = *(const int4*)&src[e];
        int4 d4 = *(const int4*)&dst[e];
        float4 w4 = *(const float4*)&ew[e];
        uint32_t p0 = atomicAdd(&cur[d4.x], 1u);
        __builtin_nontemporal_store(((uint64_t)(uint32_t)__float_as_int(w4.x) << 32) |
                                    (uint32_t)s4.x, (uint64_t*)&packed[p0]);
        uint32_t p1 = atomicAdd(&cur[d4.y], 1u);
        __builtin_nontemporal_store(((uint64_t)(uint32_t)__float_as_int(w4.y) << 32) |
                                    (uint32_t)s4.y, (uint64_t*)&packed[p1]);
        uint32_t p2 = atomicAdd(&cur[d4.z], 1u);
        __builtin_nontemporal_store(((uint64_t)(uint32_t)__float_as_int(w4.z) << 32) |
                                    (uint32_t)s4.z, (uint64_t*)&packed[p2]);
        uint32_t p3 = atomicAdd(&cur[d4.w], 1u);
        __builtin_nontemporal_store(((uint64_t)(uint32_t)__float_as_int(w4.w) << 32) |
                                    (uint32_t)s4.w, (uint64_t*)&packed[p3]);
    }
}

// ---------- deg + scale: dinv from sorted segments; bf16 table from x directly ----
__global__ void __launch_bounds__(256) k_degscale(const int* __restrict__ offs,
                                                  const int2* __restrict__ packed,
                                                  const float* __restrict__ x,
                                                  float* __restrict__ dinv,
                                                  uint16_t* __restrict__ xTh) {
    __shared__ float tile[16][132];   // [d-local][b], pad vs bank aliasing
    __shared__ float dvs[16];
    int bid = blockIdx.x;             // 0..1023
    int d0 = bid * 16;
    int t = threadIdx.x;
    int wave = t >> 6, lane = t & 63;
#pragma unroll
    for (int i = 0; i < 4; i++) {
        int dl = wave * 4 + i;
        int d = d0 + dl;
        int e0 = offs[d], e1 = offs[d + 1];
        float s = 0.f;
        for (int e = e0 + lane; e < e1; e += 64)
            s += __int_as_float(packed[e].y);
#pragma unroll
        for (int o = 32; o > 0; o >>= 1) s += __shfl_down(s, o);
        if (lane == 0) {
            float dv = rsqrtf(s + 1.0f);   // + self-loop weight 1; always > 0
            dvs[dl] = dv;
            dinv[d] = dv;
        }
    }
    int dl = t & 15, bg = t >> 4;     // 16 d-lanes x 16 b-groups
#pragma unroll
    for (int i = 0; i < 8; i++) {
        int b = bg * 8 + i;
        tile[dl][b] = x[(size_t)b * N_DIM + d0 + dl];
    }
    __syncthreads();
    int r = t >> 4, cg = t & 15;
    float dv = dvs[r];
    uint4 w;
    uint32_t* wp = (uint32_t*)&w;
#pragma unroll
    for (int j = 0; j < 4; j++) {
        float a = tile[r][cg * 8 + j * 2] * dv;
        float b = tile[r][cg * 8 + j * 2 + 1] * dv;
        wp[j] = f2bf(a) | (f2bf(b) << 16);
    }
    *(uint4*)&xTh[(size_t)(d0 + r) * B_DIM + cg * 8] = w;
}

// ---------- diffusion: TWO nodes per wave, pre-scaled table, bf16 [b][n] out ----
__global__ void __launch_bounds__(256) k_diffuse(const uint16_t* __restrict__ xTh,
                                                 const int* __restrict__ offs,
                                                 const int2* __restrict__ packed,
                                                 const float* __restrict__ dinv,
                                                 uint16_t* __restrict__ hB) {
    __shared__ uint4 ls[128];          // 8 nodes x 16 uint4 = [node][b] bf16 tile
    int wave = threadIdx.x >> 6;
    int d0 = blockIdx.x * 8 + wave * 2;   // this wave's node pair
    int lane = threadIdx.x & 63;
    int g = lane >> 4;                  // edge subgroup 0..3
    int colh = lane & 15;               // uint4 chunk within row (16 per row)
    const uint4* x4 = (const uint4*)xTh;
    int oA = offs[d0], oM = offs[d0 + 1], oB = offs[d0 + 2];  // A=[oA,oM) B=[oM,oB)
    int eA = oA + lane;
    int2 pA = (eA < oM) ? packed[eA] : make_int2(0, 0);
    int eB = oM + lane;
    int2 pB = (eB < oB) ? packed[eB] : make_int2(0, 0);
    float accA[8], accB[8];
#pragma unroll
    for (int k = 0; k < 8; k++) { accA[k] = 0.f; accB[k] = 0.f; }
    for (int base = oA; base < oM; base += 64) {
        int2 pc = pA;
        int en = base + 64 + lane;
        pA = (en < oM) ? packed[en] : make_int2(0, 0);
#pragma unroll
        for (int i = 0; i < 64; i += 4) {
            int idx = i + g;
            int sx = __shfl(pc.x, idx);
            float nm = __shfl(__int_as_float(pc.y), idx);
            uint4 xs = x4[(size_t)sx * 16 + colh];
            accA[0] = fmaf(nm, __uint_as_float(xs.x << 16), accA[0]);
            accA[1] = fmaf(nm, __uint_as_float(xs.x & 0xffff0000u), accA[1]);
            accA[2] = fmaf(nm, __uint_as_float(xs.y << 16), accA[2]);
            accA[3] = fmaf(nm, __uint_as_float(xs.y & 0xffff0000u), accA[3]);
            accA[4] = fmaf(nm, __uint_as_float(xs.z << 16), accA[4]);
            accA[5] = fmaf(nm, __uint_as_float(xs.z & 0xffff0000u), accA[5]);
            accA[6] = fmaf(nm, __uint_as_float(xs.w << 16), accA[6]);
            accA[7] = fmaf(nm, __uint_as_float(xs.w & 0xffff0000u), accA[7]);
        }
    }
    for (int base = oM; base < oB; base += 64) {
        int2 pc = pB;
        int en = base + 64 + lane;
        pB = (en < oB) ? packed[en] : make_int2(0, 0);
#pragma unroll
        for (int i = 0; i < 64; i += 4) {
            int idx = i + g;
            int sx = __shfl(pc.x, idx);
            float nm = __shfl(__int_as_float(pc.y), idx);
            uint4 xs = x4[(size_t)sx * 16 + colh];
            accB[0] = fmaf(nm, __uint_as_float(xs.x << 16), accB[0]);
            accB[1] = fmaf(nm, __uint_as_float(xs.x & 0xffff0000u), accB[1]);
            accB[2] = fmaf(nm, __uint_as_float(xs.y << 16), accB[2]);
            accB[3] = fmaf(nm, __uint_as_float(xs.y & 0xffff0000u), accB[3]);
            accB[4] = fmaf(nm, __uint_as_float(xs.z << 16), accB[4]);
            accB[5] = fmaf(nm, __uint_as_float(xs.z & 0xffff0000u), accB[5]);
            accB[6] = fmaf(nm, __uint_as_float(xs.w << 16), accB[6]);
            accB[7] = fmaf(nm, __uint_as_float(xs.w & 0xffff0000u), accB[7]);
        }
    }
#pragma unroll
    for (int off = 16; off <= 32; off <<= 1)
#pragma unroll
        for (int k = 0; k < 8; k++) {
            accA[k] += __shfl_xor(accA[k], off);
            accB[k] += __shfl_xor(accB[k], off);
        }
    int who = lane >> 4;                // 0 -> node A, 1 -> node B
    if (who < 2) {
        int dd = d0 + who;
        float dv = dinv[dd];
        uint4 sv = x4[(size_t)dd * 16 + colh];   // self row (already dinv[d]-scaled)
        float o[8];
#pragma unroll
        for (int k = 0; k < 8; k++) o[k] = (who == 0) ? accA[k] : accB[k];
        o[0] = (o[0] + __uint_as_float(sv.x << 16)) * dv;
        o[1] = (o[1] + __uint_as_float(sv.x & 0xffff0000u)) * dv;
        o[2] = (o[2] + __uint_as_float(sv.y << 16)) * dv;
        o[3] = (o[3] + __uint_as_float(sv.y & 0xffff0000u)) * dv;
        o[4] = (o[4] + __uint_as_float(sv.z << 16)) * dv;
        o[5] = (o[5] + __uint_as_float(sv.z & 0xffff0000u)) * dv;
        o[6] = (o[6] + __uint_as_float(sv.w << 16)) * dv;
        o[7] = (o[7] + __uint_as_float(sv.w & 0xffff0000u)) * dv;
        uint4 r;
        r.x = f2bf(o[0]) | (f2bf(o[1]) << 16);
        r.y = f2bf(o[2]) | (f2bf(o[3]) << 16);
        r.z = f2bf(o[4]) | (f2bf(o[5]) << 16);
        r.w = f2bf(o[6]) | (f2bf(o[7]) << 16);
        ls[(wave * 2 + who) * 16 + colh] = r;    // [node][b] tile in LDS
    }
    __syncthreads();
    int t = threadIdx.x;
    if (t < 128) {                      // one 16B hB row-chunk per thread
        const uint16_t* l16 = (const uint16_t*)ls;
        uint16_t v0 = l16[0 * 128 + t], v1 = l16[1 * 128 + t];
        uint16_t v2 = l16[2 * 128 + t], v3 = l16[3 * 128 + t];
        uint16_t v4 = l16[4 * 128 + t], v5 = l16[5 * 128 + t];
        uint16_t v6 = l16[6 * 128 + t], v7 = l16[7 * 128 + t];
        uint4 r;
        r.x = (uint32_t)v0 | ((uint32_t)v1 << 16);
        r.y = (uint32_t)v2 | ((uint32_t)v3 << 16);
        r.z = (uint32_t)v4 | ((uint32_t)v5 << 16);
        r.w = (uint32_t)v6 | ((uint32_t)v7 << 16);
        *(uint4*)&hB[(size_t)t * N_DIM + blockIdx.x * 8] = r;
    }
}

// ---------- GEMM1 (MFMA bf16, error-compensated W) -> part[kc][b][j] (NT stores) ----
__global__ void __launch_bounds__(256) k_gemm1(const float* __restrict__ W1,
                                               const uint16_t* __restrict__ hB,
                                               float* __restrict__ part) {
    int kc = blockIdx.x;               // 0..SPLITK-1
    int mt = blockIdx.y;               // 0..7
    int t = threadIdx.x, w = t >> 6, l = t & 63;
    int lr = l & 15;
    int lk = (l >> 4) * 8;
    int row = mt * 64 + w * 16 + lr;   // W1 row for A-frag
    int k0 = kc * KC;
    f32x4 acc[8] = {};
    const float* wbase = W1 + (size_t)row * N_DIM + k0 + lk;
    const uint16_t* hbase = hB + k0 + lk;
#pragma unroll 2
    for (int ks = 0; ks < KC; ks += 32) {
        float4 wa = *(const float4*)(wbase + ks);
        float4 wb = *(const float4*)(wbase + ks + 4);
        short8 bf[8];
#pragma unroll
        for (int c = 0; c < 8; c++)
            bf[c] = *(const short8*)(hbase + (size_t)(c * 16 + lr) * N_DIM + ks);
        float wv0 = wa.x, wv1 = wa.y, wv2 = wa.z, wv3 = wa.w;
        float wv4 = wb.x, wv5 = wb.y, wv6 = wb.z, wv7 = wb.w;
        short8 ahi, alo;
        uint32_t h0;
        h0 = f2bf(wv0); ahi[0] = (short)h0; alo[0] = (short)f2bf(wv0 - __uint_as_float(h0 << 16));
        h0 = f2bf(wv1); ahi[1] = (short)h0; alo[1] = (short)f2bf(wv1 - __uint_as_float(h0 << 16));
        h0 = f2bf(wv2); ahi[2] = (short)h0; alo[2] = (short)f2bf(wv2 - __uint_as_float(h0 << 16));
        h0 = f2bf(wv3); ahi[3] = (short)h0; alo[3] = (short)f2bf(wv3 - __uint_as_float(h0 << 16));
        h0 = f2bf(wv4); ahi[4] = (short)h0; alo[4] = (short)f2bf(wv4 - __uint_as_float(h0 << 16));
        h0 = f2bf(wv5); ahi[5] = (short)h0; alo[5] = (short)f2bf(wv5 - __uint_as_float(h0 << 16));
        h0 = f2bf(wv6); ahi[6] = (short)h0; alo[6] = (short)f2bf(wv6 - __uint_as_float(h0 << 16));
        h0 = f2bf(wv7); ahi[7] = (short)h0; alo[7] = (short)f2bf(wv7 - __uint_as_float(h0 << 16));
#pragma unroll
        for (int c = 0; c < 8; c++) {
            acc[c] = __builtin_amdgcn_mfma_f32_16x16x32_bf16(ahi, bf[c], acc[c], 0, 0, 0);
            acc[c] = __builtin_amdgcn_mfma_f32_16x16x32_bf16(alo, bf[c], acc[c], 0, 0, 0);
        }
    }
    float* pbase = part + (size_t)kc * (H_DIM * B_DIM);
    int j0 = mt * 64 + w * 16 + (l >> 4) * 4;
#pragma unroll
    for (int c = 0; c < 8; c++) {
        int b = c * 16 + lr;
        __builtin_nontemporal_store(acc[c], (f32x4*)&pbase[(size_t)b * H_DIM + j0]);
    }
}

// ---------- fused reduce + GEMM2 + GEMM3: per-batch block ----------
__global__ void __launch_bounds__(1024) k_tail123(const float* __restrict__ part,
                                                  const float* __restrict__ b1,
                                                  const float* __restrict__ W2,
                                                  const float* __restrict__ b2,
                                                  const float* __restrict__ Wfc,
                                                  const float* __restrict__ bfc,
                                                  float* __restrict__ out) {
    __shared__ float h1s[H_DIM];
    __shared__ float h2s[H_DIM];
    int b = blockIdx.x;                 // 0..127
    int t = threadIdx.x;
    {   // Phase R: split-K reduction (part read-once -> NT loads)
        int j = t & 511, half = t >> 9;
        const float* pb = part + (size_t)b * H_DIM + j
                        + (size_t)half * (SPLITK / 2) * (H_DIM * B_DIM);
        float acc = 0.f;
#pragma unroll
        for (int c = 0; c < SPLITK / 2; c++)
            acc += __builtin_nontemporal_load(pb + (size_t)c * (H_DIM * B_DIM));
        if (half == 0) h1s[j] = acc;
        __syncthreads();
        if (half == 1) h1s[j] = fmaxf(h1s[j] + acc + b1[j], 0.f);
        __syncthreads();
    }
    int w = t >> 6;                     // 0..15
    int l = t & 63;
    float hv[8];
#pragma unroll
    for (int k = 0; k < 8; k++) hv[k] = h1s[k * 64 + l];
#pragma unroll
    for (int it = 0; it < 4; it++) {
        int j0 = w * 32 + it * 8;
        float outv = 0.f;
#pragma unroll
        for (int jj = 0; jj < 8; jj++) {
            const float* wrow = W2 + (size_t)(j0 + jj) * H_DIM;
            float a = 0.f;
#pragma unroll
            for (int k = 0; k < 8; k++) a = fmaf(wrow[k * 64 + l], hv[k], a);
#pragma unroll
            for (int o = 1; o < 64; o <<= 1) a += __shfl_xor(a, o);
            if (l == jj) outv = a;
        }
        if (l < 8) h2s[j0 + l] = fmaxf(outv + b2[j0 + l], 0.f);
    }
    __syncthreads();
    if (w == 0) {
        float hv2[8];
#pragma unroll
        for (int k = 0; k < 8; k++) hv2[k] = h2s[k * 64 + l];
        float outv = 0.f;
#pragma unroll
        for (int c = 0; c < C_DIM; c++) {
            const float* wrow = Wfc + (size_t)c * H_DIM;
            float a = 0.f;
#pragma unroll
            for (int k = 0; k < 8; k++) a = fmaf(wrow[k * 64 + l], hv2[k], a);
#pragma unroll
            for (int o = 1; o < 64; o <<= 1) a += __shfl_xor(a, o);
            if (l == c) outv = a;
        }
        if (l < C_DIM) out[b * C_DIM + l] = outv + bfc[l];
    }
}

extern "C" void kernel_launch(void* const* d_in, const int* in_sizes, int n_in,
                              void* d_out, int out_size, void* d_ws, size_t ws_size,
                              hipStream_t stream) {
    const float* x   = (const float*)d_in[0];
    const int*   ei  = (const int*)d_in[1];
    const float* ew  = (const float*)d_in[2];
    const float* W1  = (const float*)d_in[3];
    const float* b1  = (const float*)d_in[4];
    const float* W2  = (const float*)d_in[5];
    const float* b2  = (const float*)d_in[6];
    const float* Wfc = (const float*)d_in[7];
    const float* bfc = (const float*)d_in[8];
    float* out = (float*)d_out;

    const int* src = ei;
    const int* dst = ei + E_DIM;

    char* ws = (char*)d_ws;
    size_t off = 0;
    auto alloc = [&](size_t bytes) -> void* {
        void* p = ws + off;
        off = (off + bytes + 255) & ~(size_t)255;
        return p;
    };
    uint16_t* xTh = (uint16_t*)alloc((size_t)N_DIM * B_DIM * 2);       // 4 MB bf16 [n][b] (scaled)
    int2*  packed = (int2*) alloc((size_t)E_DIM * 8);                  // 8 MB
    // scratch union (lifetimes disjoint, stream-ordered):
    //   [hist1..place2] : slab8 4 MB + grp8 128 KB
    //   [gemm1..tail123]: part 16 MB
    size_t sort_bytes = (size_t)NWG * NWORD8 * 4 + (size_t)NGRP * NWORD8 * 4;
    size_t part_bytes = (size_t)SPLITK * H_DIM * B_DIM * 4;
    char* scratch = (char*)alloc(sort_bytes > part_bytes ? sort_bytes : part_bytes);
    int*   offs   = (int*)  alloc((size_t)(N_DIM + 1) * 4);
    float* dinv   = (float*)alloc((size_t)N_DIM * 4);
    uint16_t* hB  = (uint16_t*)alloc((size_t)B_DIM * N_DIM * 2);       // 4 MB bf16 [b][n]
    uint32_t* slab = (uint32_t*)scratch;
    uint32_t* grp  = (uint32_t*)(scratch + (size_t)NWG * NWORD8 * 4);
    float* part    = (float*)scratch;      // alias: live only gemm1..tail123
    if (off > ws_size) return;

    k_hist1<<<NWG, 256, 0, stream>>>(dst, slab);
    k_scanA8<<<NWG, 128, 0, stream>>>(slab, grp);
    k_scanBC8<<<1, 1024, 0, stream>>>(grp, offs);
    k_place2<<<NWG, 256, 0, stream>>>(src, dst, ew, slab, grp, offs, packed);
    k_degscale<<<N_DIM / 16, 256, 0, stream>>>(offs, packed, x, dinv, xTh);
    k_diffuse<<<N_DIM / 8, 256, 0, stream>>>(xTh, offs, packed, dinv, hB);
    k_gemm1<<<dim3(SPLITK, H_DIM / 64), 256, 0, stream>>>(W1, hB, part);
    k_tail123<<<B_DIM, 1024, 0, stream>>>(part, b1, W2, b2, Wfc, bfc, out);
}

// Round 24
// 117.380 us; speedup vs baseline: 1.0910x; 1.0910x over previous
//
#include <hip/hip_runtime.h>
#include <hip/hip_bf16.h>
#include <stdint.h>

#define B_DIM 128
#define N_DIM 16384
#define E_DIM 1048576
#define H_DIM 512
#define C_DIM 10
#define NWG 256               // wgs for hist/place
#define CHUNK (E_DIM / NWG)   // 4096 edges per wg
#define NWORD8 (N_DIM / 4)    // 4096 words, 4 x 8-bit bins each
#define NGRP 8                // scan groups
#define WPG (NWG / NGRP)      // 32 wgs per group
#define SPLITK 64
#define KC (N_DIM / SPLITK)   // 256

typedef __attribute__((ext_vector_type(8))) short short8;   // 8 bf16 = 4 VGPRs
typedef __attribute__((ext_vector_type(4))) float f32x4;    // MFMA accumulator

// float -> bf16 round-to-nearest-even (finite inputs)
__device__ __forceinline__ uint32_t f2bf(float f) {
    uint32_t u = __float_as_uint(f);
    return (u + 0x7fffu + ((u >> 16) & 1u)) >> 16;
}

// ---------- 8-bit LDS histogram of dst (int4-vectorized loads) ----------
__global__ void __launch_bounds__(256) k_hist1(const int* __restrict__ dst,
                                               uint32_t* __restrict__ slab) {
    __shared__ uint32_t ls[NWORD8];   // 16 KB
    int bid = blockIdx.x, t = threadIdx.x;
#pragma unroll
    for (int i = 0; i < NWORD8 / 256; i++) ls[i * 256 + t] = 0;
    __syncthreads();
#pragma unroll
    for (int i = 0; i < CHUNK / 1024; i++) {   // 4 iters x 4 edges
        int4 d4 = *(const int4*)&dst[bid * CHUNK + i * 1024 + t * 4];
        atomicAdd(&ls[d4.x >> 2], 1u << ((d4.x & 3) << 3));
        atomicAdd(&ls[d4.y >> 2], 1u << ((d4.y & 3) << 3));
        atomicAdd(&ls[d4.z >> 2], 1u << ((d4.z & 3) << 3));
        atomicAdd(&ls[d4.w >> 2], 1u << ((d4.w & 3) << 3));
    }
    __syncthreads();
#pragma unroll
    for (int i = 0; i < NWORD8 / 256; i++)
        slab[(size_t)bid * NWORD8 + i * 256 + t] = ls[i * 256 + t];
}

// ---------- within-group (32 wgs) in-place exclusive prefix (SWAR 4x8-bit) ----
__global__ void __launch_bounds__(128) k_scanA8(uint32_t* __restrict__ slab,
                                                uint32_t* __restrict__ grp) {
    int b = blockIdx.x;                    // 0..255
    int g = b >> 5;                        // group 0..7
    int j = (b & 31) * 128 + threadIdx.x;  // word 0..4095
    uint32_t run = 0;                      // 4 byte-fields, each stays < 256
    for (int w = g * WPG; w < (g + 1) * WPG; w++) {
        uint32_t c = slab[(size_t)w * NWORD8 + j];
        slab[(size_t)w * NWORD8 + j] = run;
        run += c;                          // bytewise-safe (no field overflow)
    }
    grp[(size_t)g * NWORD8 + j] = run;
}

// ---------- cross-group prefix (in-place) + global bin scan -> CSR offs ----------
__global__ void __launch_bounds__(1024) k_scanBC8(uint32_t* __restrict__ grp,
                                                  int* __restrict__ offs) {
    __shared__ uint32_t part[1024];
    int t = threadIdx.x;
    uint32_t tw[4];
    int loc[16];
    uint32_t s = 0;
    int k = 0;
#pragma unroll
    for (int i = 0; i < 4; i++) {
        int j = t * 4 + i;
        uint32_t run = 0;
#pragma unroll
        for (int g = 0; g < NGRP; g++) {
            uint32_t c = grp[(size_t)g * NWORD8 + j];
            grp[(size_t)g * NWORD8 + j] = run;
            run += c;                      // bytewise-safe (totals < 256)
        }
        tw[i] = run;
#pragma unroll
        for (int b4 = 0; b4 < 4; b4++) {
            loc[k] = (int)s;
            s += (tw[i] >> (b4 * 8)) & 0xffu;
            k++;
        }
    }
    part[t] = s;
    __syncthreads();
    for (int off = 1; off < 1024; off <<= 1) {
        uint32_t v = (t >= off) ? part[t - off] : 0;
        __syncthreads();
        part[t] += v;
        __syncthreads();
    }
    uint32_t ex = (t == 0) ? 0 : part[t - 1];
#pragma unroll
    for (int i = 0; i < 16; i++) offs[t * 16 + i] = (int)(ex + loc[i]);
    if (t == 1023) offs[N_DIM] = (int)part[1023];
}

// ---------- atomic-free (global) placement: LDS cursor per wg (int4 loads) ----
__global__ void __launch_bounds__(256) k_place2(const int* __restrict__ src,
                                                const int* __restrict__ dst,
                                                const float* __restrict__ ew,
                                                const uint32_t* __restrict__ slab,
                                                const uint32_t* __restrict__ grp,
                                                const int* __restrict__ offs,
                                                int2* __restrict__ packed) {
    __shared__ uint32_t cur[N_DIM];   // 64 KB
    int w = blockIdx.x, t = threadIdx.x;
    int g = w >> 5;
#pragma unroll
    for (int i = 0; i < NWORD8 / 256; i++) {
        int j = i * 256 + t;
        uint32_t pv = slab[(size_t)w * NWORD8 + j];
        uint32_t gv = grp[(size_t)g * NWORD8 + j];
        int4 o = *(const int4*)&offs[4 * j];
        cur[4 * j + 0] = (uint32_t)o.x + (gv & 0xffu) + (pv & 0xffu);
        cur[4 * j + 1] = (uint32_t)o.y + ((gv >> 8) & 0xffu) + ((pv >> 8) & 0xffu);
        cur[4 * j + 2] = (uint32_t)o.z + ((gv >> 16) & 0xffu) + ((pv >> 16) & 0xffu);
        cur[4 * j + 3] = (uint32_t)o.w + (gv >> 24) + (pv >> 24);
    }
    __syncthreads();
#pragma unroll
    for (int i = 0; i < CHUNK / 1024; i++) {   // 4 iters x 4 edges, 16B loads
        int e = w * CHUNK + i * 1024 + t * 4;
        int4 s4 = *(const int4*)&src[e];
        int4 d4 = *(const int4*)&dst[e];
        float4 w4 = *(const float4*)&ew[e];
        uint32_t p0 = atomicAdd(&cur[d4.x], 1u);
        packed[p0] = make_int2(s4.x, __float_as_int(w4.x));
        uint32_t p1 = atomicAdd(&cur[d4.y], 1u);
        packed[p1] = make_int2(s4.y, __float_as_int(w4.y));
        uint32_t p2 = atomicAdd(&cur[d4.z], 1u);
        packed[p2] = make_int2(s4.z, __float_as_int(w4.z));
        uint32_t p3 = atomicAdd(&cur[d4.w], 1u);
        packed[p3] = make_int2(s4.w, __float_as_int(w4.w));
    }
}

// ---------- deg + scale: dinv from sorted segments; bf16 table from x directly ----
__global__ void __launch_bounds__(256) k_degscale(const int* __restrict__ offs,
                                                  const int2* __restrict__ packed,
                                                  const float* __restrict__ x,
                                                  float* __restrict__ dinv,
                                                  uint16_t* __restrict__ xTh) {
    __shared__ float tile[16][132];   // [d-local][b], pad vs bank aliasing
    __shared__ float dvs[16];
    int bid = blockIdx.x;             // 0..1023
    int d0 = bid * 16;
    int t = threadIdx.x;
    int wave = t >> 6, lane = t & 63;
#pragma unroll
    for (int i = 0; i < 4; i++) {
        int dl = wave * 4 + i;
        int d = d0 + dl;
        int e0 = offs[d], e1 = offs[d + 1];
        float s = 0.f;
        for (int e = e0 + lane; e < e1; e += 64)
            s += __int_as_float(packed[e].y);
#pragma unroll
        for (int o = 32; o > 0; o >>= 1) s += __shfl_down(s, o);
        if (lane == 0) {
            float dv = rsqrtf(s + 1.0f);   // + self-loop weight 1; always > 0
            dvs[dl] = dv;
            dinv[d] = dv;
        }
    }
    int dl = t & 15, bg = t >> 4;     // 16 d-lanes x 16 b-groups
#pragma unroll
    for (int i = 0; i < 8; i++) {
        int b = bg * 8 + i;
        tile[dl][b] = x[(size_t)b * N_DIM + d0 + dl];
    }
    __syncthreads();
    int r = t >> 4, cg = t & 15;
    float dv = dvs[r];
    uint4 w;
    uint32_t* wp = (uint32_t*)&w;
#pragma unroll
    for (int j = 0; j < 4; j++) {
        float a = tile[r][cg * 8 + j * 2] * dv;
        float b = tile[r][cg * 8 + j * 2 + 1] * dv;
        wp[j] = f2bf(a) | (f2bf(b) << 16);
    }
    *(uint4*)&xTh[(size_t)(d0 + r) * B_DIM + cg * 8] = w;
}

// ---------- diffusion: TWO nodes per wave, pre-scaled table, bf16 [b][n] out ----
__global__ void __launch_bounds__(256) k_diffuse(const uint16_t* __restrict__ xTh,
                                                 const int* __restrict__ offs,
                                                 const int2* __restrict__ packed,
                                                 const float* __restrict__ dinv,
                                                 uint16_t* __restrict__ hB) {
    __shared__ uint4 ls[128];          // 8 nodes x 16 uint4 = [node][b] bf16 tile
    int wave = threadIdx.x >> 6;
    int d0 = blockIdx.x * 8 + wave * 2;   // this wave's node pair
    int lane = threadIdx.x & 63;
    int g = lane >> 4;                  // edge subgroup 0..3
    int colh = lane & 15;               // uint4 chunk within row (16 per row)
    const uint4* x4 = (const uint4*)xTh;
    int oA = offs[d0], oM = offs[d0 + 1], oB = offs[d0 + 2];  // A=[oA,oM) B=[oM,oB)
    int eA = oA + lane;
    int2 pA = (eA < oM) ? packed[eA] : make_int2(0, 0);
    int eB = oM + lane;
    int2 pB = (eB < oB) ? packed[eB] : make_int2(0, 0);
    float accA[8], accB[8];
#pragma unroll
    for (int k = 0; k < 8; k++) { accA[k] = 0.f; accB[k] = 0.f; }
    for (int base = oA; base < oM; base += 64) {
        int2 pc = pA;
        int en = base + 64 + lane;
        pA = (en < oM) ? packed[en] : make_int2(0, 0);
#pragma unroll
        for (int i = 0; i < 64; i += 4) {
            int idx = i + g;
            int sx = __shfl(pc.x, idx);
            float nm = __shfl(__int_as_float(pc.y), idx);
            uint4 xs = x4[(size_t)sx * 16 + colh];
            accA[0] = fmaf(nm, __uint_as_float(xs.x << 16), accA[0]);
            accA[1] = fmaf(nm, __uint_as_float(xs.x & 0xffff0000u), accA[1]);
            accA[2] = fmaf(nm, __uint_as_float(xs.y << 16), accA[2]);
            accA[3] = fmaf(nm, __uint_as_float(xs.y & 0xffff0000u), accA[3]);
            accA[4] = fmaf(nm, __uint_as_float(xs.z << 16), accA[4]);
            accA[5] = fmaf(nm, __uint_as_float(xs.z & 0xffff0000u), accA[5]);
            accA[6] = fmaf(nm, __uint_as_float(xs.w << 16), accA[6]);
            accA[7] = fmaf(nm, __uint_as_float(xs.w & 0xffff0000u), accA[7]);
        }
    }
    for (int base = oM; base < oB; base += 64) {
        int2 pc = pB;
        int en = base + 64 + lane;
        pB = (en < oB) ? packed[en] : make_int2(0, 0);
#pragma unroll
        for (int i = 0; i < 64; i += 4) {
            int idx = i + g;
            int sx = __shfl(pc.x, idx);
            float nm = __shfl(__int_as_float(pc.y), idx);
            uint4 xs = x4[(size_t)sx * 16 + colh];
            accB[0] = fmaf(nm, __uint_as_float(xs.x << 16), accB[0]);
            accB[1] = fmaf(nm, __uint_as_float(xs.x & 0xffff0000u), accB[1]);
            accB[2] = fmaf(nm, __uint_as_float(xs.y << 16), accB[2]);
            accB[3] = fmaf(nm, __uint_as_float(xs.y & 0xffff0000u), accB[3]);
            accB[4] = fmaf(nm, __uint_as_float(xs.z << 16), accB[4]);
            accB[5] = fmaf(nm, __uint_as_float(xs.z & 0xffff0000u), accB[5]);
            accB[6] = fmaf(nm, __uint_as_float(xs.w << 16), accB[6]);
            accB[7] = fmaf(nm, __uint_as_float(xs.w & 0xffff0000u), accB[7]);
        }
    }
#pragma unroll
    for (int off = 16; off <= 32; off <<= 1)
#pragma unroll
        for (int k = 0; k < 8; k++) {
            accA[k] += __shfl_xor(accA[k], off);
            accB[k] += __shfl_xor(accB[k], off);
        }
    int who = lane >> 4;                // 0 -> node A, 1 -> node B
    if (who < 2) {
        int dd = d0 + who;
        float dv = dinv[dd];
        uint4 sv = x4[(size_t)dd * 16 + colh];   // self row (already dinv[d]-scaled)
        float o[8];
#pragma unroll
        for (int k = 0; k < 8; k++) o[k] = (who == 0) ? accA[k] : accB[k];
        o[0] = (o[0] + __uint_as_float(sv.x << 16)) * dv;
        o[1] = (o[1] + __uint_as_float(sv.x & 0xffff0000u)) * dv;
        o[2] = (o[2] + __uint_as_float(sv.y << 16)) * dv;
        o[3] = (o[3] + __uint_as_float(sv.y & 0xffff0000u)) * dv;
        o[4] = (o[4] + __uint_as_float(sv.z << 16)) * dv;
        o[5] = (o[5] + __uint_as_float(sv.z & 0xffff0000u)) * dv;
        o[6] = (o[6] + __uint_as_float(sv.w << 16)) * dv;
        o[7] = (o[7] + __uint_as_float(sv.w & 0xffff0000u)) * dv;
        uint4 r;
        r.x = f2bf(o[0]) | (f2bf(o[1]) << 16);
        r.y = f2bf(o[2]) | (f2bf(o[3]) << 16);
        r.z = f2bf(o[4]) | (f2bf(o[5]) << 16);
        r.w = f2bf(o[6]) | (f2bf(o[7]) << 16);
        ls[(wave * 2 + who) * 16 + colh] = r;    // [node][b] tile in LDS
    }
    __syncthreads();
    int t = threadIdx.x;
    if (t < 128) {                      // one 16B hB row-chunk per thread
        const uint16_t* l16 = (const uint16_t*)ls;
        uint16_t v0 = l16[0 * 128 + t], v1 = l16[1 * 128 + t];
        uint16_t v2 = l16[2 * 128 + t], v3 = l16[3 * 128 + t];
        uint16_t v4 = l16[4 * 128 + t], v5 = l16[5 * 128 + t];
        uint16_t v6 = l16[6 * 128 + t], v7 = l16[7 * 128 + t];
        uint4 r;
        r.x = (uint32_t)v0 | ((uint32_t)v1 << 16);
        r.y = (uint32_t)v2 | ((uint32_t)v3 << 16);
        r.z = (uint32_t)v4 | ((uint32_t)v5 << 16);
        r.w = (uint32_t)v6 | ((uint32_t)v7 << 16);
        *(uint4*)&hB[(size_t)t * N_DIM + blockIdx.x * 8] = r;
    }
}

// ---------- GEMM1 (MFMA bf16, error-compensated W) -> part[kc][b][j] ----------
__global__ void __launch_bounds__(256) k_gemm1(const float* __restrict__ W1,
                                               const uint16_t* __restrict__ hB,
                                               float* __restrict__ part) {
    int kc = blockIdx.x;               // 0..SPLITK-1
    int mt = blockIdx.y;               // 0..7
    int t = threadIdx.x, w = t >> 6, l = t & 63;
    int lr = l & 15;
    int lk = (l >> 4) * 8;
    int row = mt * 64 + w * 16 + lr;   // W1 row for A-frag
    int k0 = kc * KC;
    f32x4 acc[8] = {};
    const float* wbase = W1 + (size_t)row * N_DIM + k0 + lk;
    const uint16_t* hbase = hB + k0 + lk;
#pragma unroll 2
    for (int ks = 0; ks < KC; ks += 32) {
        float4 wa = *(const float4*)(wbase + ks);
        float4 wb = *(const float4*)(wbase + ks + 4);
        short8 bf[8];
#pragma unroll
        for (int c = 0; c < 8; c++)
            bf[c] = *(const short8*)(hbase + (size_t)(c * 16 + lr) * N_DIM + ks);
        float wv0 = wa.x, wv1 = wa.y, wv2 = wa.z, wv3 = wa.w;
        float wv4 = wb.x, wv5 = wb.y, wv6 = wb.z, wv7 = wb.w;
        short8 ahi, alo;
        uint32_t h0;
        h0 = f2bf(wv0); ahi[0] = (short)h0; alo[0] = (short)f2bf(wv0 - __uint_as_float(h0 << 16));
        h0 = f2bf(wv1); ahi[1] = (short)h0; alo[1] = (short)f2bf(wv1 - __uint_as_float(h0 << 16));
        h0 = f2bf(wv2); ahi[2] = (short)h0; alo[2] = (short)f2bf(wv2 - __uint_as_float(h0 << 16));
        h0 = f2bf(wv3); ahi[3] = (short)h0; alo[3] = (short)f2bf(wv3 - __uint_as_float(h0 << 16));
        h0 = f2bf(wv4); ahi[4] = (short)h0; alo[4] = (short)f2bf(wv4 - __uint_as_float(h0 << 16));
        h0 = f2bf(wv5); ahi[5] = (short)h0; alo[5] = (short)f2bf(wv5 - __uint_as_float(h0 << 16));
        h0 = f2bf(wv6); ahi[6] = (short)h0; alo[6] = (short)f2bf(wv6 - __uint_as_float(h0 << 16));
        h0 = f2bf(wv7); ahi[7] = (short)h0; alo[7] = (short)f2bf(wv7 - __uint_as_float(h0 << 16));
#pragma unroll
        for (int c = 0; c < 8; c++) {
            acc[c] = __builtin_amdgcn_mfma_f32_16x16x32_bf16(ahi, bf[c], acc[c], 0, 0, 0);
            acc[c] = __builtin_amdgcn_mfma_f32_16x16x32_bf16(alo, bf[c], acc[c], 0, 0, 0);
        }
    }
    float* pbase = part + (size_t)kc * (H_DIM * B_DIM);
    int j0 = mt * 64 + w * 16 + (l >> 4) * 4;
#pragma unroll
    for (int c = 0; c < 8; c++) {
        int b = c * 16 + lr;
        *(f32x4*)&pbase[(size_t)b * H_DIM + j0] = acc[c];
    }
}

// ---------- fused reduce + GEMM2 + GEMM3: per-batch block ----------
__global__ void __launch_bounds__(1024) k_tail123(const float* __restrict__ part,
                                                  const float* __restrict__ b1,
                                                  const float* __restrict__ W2,
                                                  const float* __restrict__ b2,
                                                  const float* __restrict__ Wfc,
                                                  const float* __restrict__ bfc,
                                                  float* __restrict__ out) {
    __shared__ float h1s[H_DIM];
    __shared__ float h2s[H_DIM];
    int b = blockIdx.x;                 // 0..127
    int t = threadIdx.x;
    {   // Phase R: split-K reduction
        int j = t & 511, half = t >> 9;
        const float* pb = part + (size_t)b * H_DIM + j
                        + (size_t)half * (SPLITK / 2) * (H_DIM * B_DIM);
        float acc = 0.f;
#pragma unroll
        for (int c = 0; c < SPLITK / 2; c++)
            acc += pb[(size_t)c * (H_DIM * B_DIM)];
        if (half == 0) h1s[j] = acc;
        __syncthreads();
        if (half == 1) h1s[j] = fmaxf(h1s[j] + acc + b1[j], 0.f);
        __syncthreads();
    }
    int w = t >> 6;                     // 0..15
    int l = t & 63;
    float hv[8];
#pragma unroll
    for (int k = 0; k < 8; k++) hv[k] = h1s[k * 64 + l];
#pragma unroll
    for (int it = 0; it < 4; it++) {
        int j0 = w * 32 + it * 8;
        float outv = 0.f;
#pragma unroll
        for (int jj = 0; jj < 8; jj++) {
            const float* wrow = W2 + (size_t)(j0 + jj) * H_DIM;
            float a = 0.f;
#pragma unroll
            for (int k = 0; k < 8; k++) a = fmaf(wrow[k * 64 + l], hv[k], a);
#pragma unroll
            for (int o = 1; o < 64; o <<= 1) a += __shfl_xor(a, o);
            if (l == jj) outv = a;
        }
        if (l < 8) h2s[j0 + l] = fmaxf(outv + b2[j0 + l], 0.f);
    }
    __syncthreads();
    if (w == 0) {
        float hv2[8];
#pragma unroll
        for (int k = 0; k < 8; k++) hv2[k] = h2s[k * 64 + l];
        float outv = 0.f;
#pragma unroll
        for (int c = 0; c < C_DIM; c++) {
            const float* wrow = Wfc + (size_t)c * H_DIM;
            float a = 0.f;
#pragma unroll
            for (int k = 0; k < 8; k++) a = fmaf(wrow[k * 64 + l], hv2[k], a);
#pragma unroll
            for (int o = 1; o < 64; o <<= 1) a += __shfl_xor(a, o);
            if (l == c) outv = a;
        }
        if (l < C_DIM) out[b * C_DIM + l] = outv + bfc[l];
    }
}

extern "C" void kernel_launch(void* const* d_in, const int* in_sizes, int n_in,
                              void* d_out, int out_size, void* d_ws, size_t ws_size,
                              hipStream_t stream) {
    const float* x   = (const float*)d_in[0];
    const int*   ei  = (const int*)d_in[1];
    const float* ew  = (const float*)d_in[2];
    const float* W1  = (const float*)d_in[3];
    const float* b1  = (const float*)d_in[4];
    const float* W2  = (const float*)d_in[5];
    const float* b2  = (const float*)d_in[6];
    const float* Wfc = (const float*)d_in[7];
    const float* bfc = (const float*)d_in[8];
    float* out = (float*)d_out;

    const int* src = ei;
    const int* dst = ei + E_DIM;

    char* ws = (char*)d_ws;
    size_t off = 0;
    auto alloc = [&](size_t bytes) -> void* {
        void* p = ws + off;
        off = (off + bytes + 255) & ~(size_t)255;
        return p;
    };
    uint16_t* xTh = (uint16_t*)alloc((size_t)N_DIM * B_DIM * 2);       // 4 MB bf16 [n][b] (scaled)
    int2*  packed = (int2*) alloc((size_t)E_DIM * 8);                  // 8 MB
    // scratch union (lifetimes disjoint, stream-ordered):
    //   [hist1..place2] : slab8 4 MB + grp8 128 KB
    //   [gemm1..tail123]: part 16 MB
    size_t sort_bytes = (size_t)NWG * NWORD8 * 4 + (size_t)NGRP * NWORD8 * 4;
    size_t part_bytes = (size_t)SPLITK * H_DIM * B_DIM * 4;
    char* scratch = (char*)alloc(sort_bytes > part_bytes ? sort_bytes : part_bytes);
    int*   offs   = (int*)  alloc((size_t)(N_DIM + 1) * 4);
    float* dinv   = (float*)alloc((size_t)N_DIM * 4);
    uint16_t* hB  = (uint16_t*)alloc((size_t)B_DIM * N_DIM * 2);       // 4 MB bf16 [b][n]
    uint32_t* slab = (uint32_t*)scratch;
    uint32_t* grp  = (uint32_t*)(scratch + (size_t)NWG * NWORD8 * 4);
    float* part    = (float*)scratch;      // alias: live only gemm1..tail123
    if (off > ws_size) return;

    k_hist1<<<NWG, 256, 0, stream>>>(dst, slab);
    k_scanA8<<<NWG, 128, 0, stream>>>(slab, grp);
    k_scanBC8<<<1, 1024, 0, stream>>>(grp, offs);
    k_place2<<<NWG, 256, 0, stream>>>(src, dst, ew, slab, grp, offs, packed);
    k_degscale<<<N_DIM / 16, 256, 0, stream>>>(offs, packed, x, dinv, xTh);
    k_diffuse<<<N_DIM / 8, 256, 0, stream>>>(xTh, offs, packed, dinv, hB);
    k_gemm1<<<dim3(SPLITK, H_DIM / 64), 256, 0, stream>>>(W1, hB, part);
    k_tail123<<<B_DIM, 1024, 0, stream>>>(part, b1, W2, b2, Wfc, bfc, out);
}

// Round 25
// 115.446 us; speedup vs baseline: 1.1092x; 1.0168x over previous
//
#include <hip/hip_runtime.h>
#include <hip/hip_bf16.h>
#include <stdint.h>

#define B_DIM 128
#define N_DIM 16384
#define E_DIM 1048576
#define H_DIM 512
#define C_DIM 10
#define NWG 256               // wgs for hist/place
#define CHUNK (E_DIM / NWG)   // 4096 edges per wg
#define NWORD8 (N_DIM / 4)    // 4096 words, 4 x 8-bit bins each
#define NGRP 8                // scan groups
#define WPG (NWG / NGRP)      // 32 wgs per group
#define SPLITK 64
#define KC (N_DIM / SPLITK)   // 256
#define WMASK 0xFFFFC000u     // top 18 bits of f32 (w in [0,1): sign=0, 8exp+9mant)
#define SMASK 0x3FFFu         // low 14 bits: src node id

typedef __attribute__((ext_vector_type(8))) short short8;   // 8 bf16 = 4 VGPRs
typedef __attribute__((ext_vector_type(4))) float f32x4;    // MFMA accumulator

// float -> bf16 round-to-nearest-even (finite inputs)
__device__ __forceinline__ uint32_t f2bf(float f) {
    uint32_t u = __float_as_uint(f);
    return (u + 0x7fffu + ((u >> 16) & 1u)) >> 16;
}

// encode edge: 18-bit rounded weight | 14-bit src (w in [0,1) => no sign/overflow issue)
__device__ __forceinline__ uint32_t encE(int s, float w) {
    uint32_t wb = __float_as_uint(w);
    return ((wb + 0x2000u) & WMASK) | (uint32_t)s;
}

// ---------- 8-bit LDS histogram of dst (int4-vectorized loads) ----------
__global__ void __launch_bounds__(256) k_hist1(const int* __restrict__ dst,
                                               uint32_t* __restrict__ slab) {
    __shared__ uint32_t ls[NWORD8];   // 16 KB
    int bid = blockIdx.x, t = threadIdx.x;
#pragma unroll
    for (int i = 0; i < NWORD8 / 256; i++) ls[i * 256 + t] = 0;
    __syncthreads();
#pragma unroll
    for (int i = 0; i < CHUNK / 1024; i++) {   // 4 iters x 4 edges
        int4 d4 = *(const int4*)&dst[bid * CHUNK + i * 1024 + t * 4];
        atomicAdd(&ls[d4.x >> 2], 1u << ((d4.x & 3) << 3));
        atomicAdd(&ls[d4.y >> 2], 1u << ((d4.y & 3) << 3));
        atomicAdd(&ls[d4.z >> 2], 1u << ((d4.z & 3) << 3));
        atomicAdd(&ls[d4.w >> 2], 1u << ((d4.w & 3) << 3));
    }
    __syncthreads();
#pragma unroll
    for (int i = 0; i < NWORD8 / 256; i++)
        slab[(size_t)bid * NWORD8 + i * 256 + t] = ls[i * 256 + t];
}

// ---------- within-group (32 wgs) in-place exclusive prefix (SWAR 4x8-bit) ----
__global__ void __launch_bounds__(128) k_scanA8(uint32_t* __restrict__ slab,
                                                uint32_t* __restrict__ grp) {
    int b = blockIdx.x;                    // 0..255
    int g = b >> 5;                        // group 0..7
    int j = (b & 31) * 128 + threadIdx.x;  // word 0..4095
    uint32_t run = 0;                      // 4 byte-fields, each stays < 256
    for (int w = g * WPG; w < (g + 1) * WPG; w++) {
        uint32_t c = slab[(size_t)w * NWORD8 + j];
        slab[(size_t)w * NWORD8 + j] = run;
        run += c;                          // bytewise-safe (no field overflow)
    }
    grp[(size_t)g * NWORD8 + j] = run;
}

// ---------- cross-group prefix (in-place) + global bin scan -> CSR offs ----------
__global__ void __launch_bounds__(1024) k_scanBC8(uint32_t* __restrict__ grp,
                                                  int* __restrict__ offs) {
    __shared__ uint32_t part[1024];
    int t = threadIdx.x;
    uint32_t tw[4];
    int loc[16];
    uint32_t s = 0;
    int k = 0;
#pragma unroll
    for (int i = 0; i < 4; i++) {
        int j = t * 4 + i;
        uint32_t run = 0;
#pragma unroll
        for (int g = 0; g < NGRP; g++) {
            uint32_t c = grp[(size_t)g * NWORD8 + j];
            grp[(size_t)g * NWORD8 + j] = run;
            run += c;                      // bytewise-safe (totals < 256)
        }
        tw[i] = run;
#pragma unroll
        for (int b4 = 0; b4 < 4; b4++) {
            loc[k] = (int)s;
            s += (tw[i] >> (b4 * 8)) & 0xffu;
            k++;
        }
    }
    part[t] = s;
    __syncthreads();
    for (int off = 1; off < 1024; off <<= 1) {
        uint32_t v = (t >= off) ? part[t - off] : 0;
        __syncthreads();
        part[t] += v;
        __syncthreads();
    }
    uint32_t ex = (t == 0) ? 0 : part[t - 1];
#pragma unroll
    for (int i = 0; i < 16; i++) offs[t * 16 + i] = (int)(ex + loc[i]);
    if (t == 1023) offs[N_DIM] = (int)part[1023];
}

// ---------- atomic-free (global) placement: LDS cursor per wg (int4 loads),
// 4-byte encoded edge records ----------
__global__ void __launch_bounds__(256) k_place2(const int* __restrict__ src,
                                                const int* __restrict__ dst,
                                                const float* __restrict__ ew,
                                                const uint32_t* __restrict__ slab,
                                                const uint32_t* __restrict__ grp,
                                                const int* __restrict__ offs,
                                                uint32_t* __restrict__ packed) {
    __shared__ uint32_t cur[N_DIM];   // 64 KB
    int w = blockIdx.x, t = threadIdx.x;
    int g = w >> 5;
#pragma unroll
    for (int i = 0; i < NWORD8 / 256; i++) {
        int j = i * 256 + t;
        uint32_t pv = slab[(size_t)w * NWORD8 + j];
        uint32_t gv = grp[(size_t)g * NWORD8 + j];
        int4 o = *(const int4*)&offs[4 * j];
        cur[4 * j + 0] = (uint32_t)o.x + (gv & 0xffu) + (pv & 0xffu);
        cur[4 * j + 1] = (uint32_t)o.y + ((gv >> 8) & 0xffu) + ((pv >> 8) & 0xffu);
        cur[4 * j + 2] = (uint32_t)o.z + ((gv >> 16) & 0xffu) + ((pv >> 16) & 0xffu);
        cur[4 * j + 3] = (uint32_t)o.w + (gv >> 24) + (pv >> 24);
    }
    __syncthreads();
#pragma unroll
    for (int i = 0; i < CHUNK / 1024; i++) {   // 4 iters x 4 edges, 16B loads
        int e = w * CHUNK + i * 1024 + t * 4;
        int4 s4 = *(const int4*)&src[e];
        int4 d4 = *(const int4*)&dst[e];
        float4 w4 = *(const float4*)&ew[e];
        uint32_t p0 = atomicAdd(&cur[d4.x], 1u);
        packed[p0] = encE(s4.x, w4.x);
        uint32_t p1 = atomicAdd(&cur[d4.y], 1u);
        packed[p1] = encE(s4.y, w4.y);
        uint32_t p2 = atomicAdd(&cur[d4.z], 1u);
        packed[p2] = encE(s4.z, w4.z);
        uint32_t p3 = atomicAdd(&cur[d4.w], 1u);
        packed[p3] = encE(s4.w, w4.w);
    }
}

// ---------- deg + scale: dinv from sorted segments; bf16 table from x directly ----
__global__ void __launch_bounds__(256) k_degscale(const int* __restrict__ offs,
                                                  const uint32_t* __restrict__ packed,
                                                  const float* __restrict__ x,
                                                  float* __restrict__ dinv,
                                                  uint16_t* __restrict__ xTh) {
    __shared__ float tile[16][132];   // [d-local][b], pad vs bank aliasing
    __shared__ float dvs[16];
    int bid = blockIdx.x;             // 0..1023
    int d0 = bid * 16;
    int t = threadIdx.x;
    int wave = t >> 6, lane = t & 63;
#pragma unroll
    for (int i = 0; i < 4; i++) {
        int dl = wave * 4 + i;
        int d = d0 + dl;
        int e0 = offs[d], e1 = offs[d + 1];
        float s = 0.f;
        for (int e = e0 + lane; e < e1; e += 64)
            s += __uint_as_float(packed[e] & WMASK);
#pragma unroll
        for (int o = 32; o > 0; o >>= 1) s += __shfl_down(s, o);
        if (lane == 0) {
            float dv = rsqrtf(s + 1.0f);   // + self-loop weight 1; always > 0
            dvs[dl] = dv;
            dinv[d] = dv;
        }
    }
    int dl = t & 15, bg = t >> 4;     // 16 d-lanes x 16 b-groups
#pragma unroll
    for (int i = 0; i < 8; i++) {
        int b = bg * 8 + i;
        tile[dl][b] = x[(size_t)b * N_DIM + d0 + dl];
    }
    __syncthreads();
    int r = t >> 4, cg = t & 15;
    float dv = dvs[r];
    uint4 w;
    uint32_t* wp = (uint32_t*)&w;
#pragma unroll
    for (int j = 0; j < 4; j++) {
        float a = tile[r][cg * 8 + j * 2] * dv;
        float b = tile[r][cg * 8 + j * 2 + 1] * dv;
        wp[j] = f2bf(a) | (f2bf(b) << 16);
    }
    *(uint4*)&xTh[(size_t)(d0 + r) * B_DIM + cg * 8] = w;
}

// ---------- diffusion: TWO nodes per wave, 4B edge records (single shfl),
// pre-scaled table, bf16 [b][n] out ----------
__global__ void __launch_bounds__(256) k_diffuse(const uint16_t* __restrict__ xTh,
                                                 const int* __restrict__ offs,
                                                 const uint32_t* __restrict__ packed,
                                                 const float* __restrict__ dinv,
                                                 uint16_t* __restrict__ hB) {
    __shared__ uint4 ls[128];          // 8 nodes x 16 uint4 = [node][b] bf16 tile
    int wave = threadIdx.x >> 6;
    int d0 = blockIdx.x * 8 + wave * 2;   // this wave's node pair
    int lane = threadIdx.x & 63;
    int g = lane >> 4;                  // edge subgroup 0..3
    int colh = lane & 15;               // uint4 chunk within row (16 per row)
    const uint4* x4 = (const uint4*)xTh;
    int oA = offs[d0], oM = offs[d0 + 1], oB = offs[d0 + 2];  // A=[oA,oM) B=[oM,oB)
    int eA = oA + lane;
    uint32_t pA = (eA < oM) ? packed[eA] : 0u;   // enc 0 => w=0, inert
    int eB = oM + lane;
    uint32_t pB = (eB < oB) ? packed[eB] : 0u;
    float accA[8], accB[8];
#pragma unroll
    for (int k = 0; k < 8; k++) { accA[k] = 0.f; accB[k] = 0.f; }
    for (int base = oA; base < oM; base += 64) {
        uint32_t pc = pA;
        int en = base + 64 + lane;
        pA = (en < oM) ? packed[en] : 0u;
#pragma unroll
        for (int i = 0; i < 64; i += 4) {
            uint32_t ev = (uint32_t)__shfl((int)pc, i + g);
            int sx = (int)(ev & SMASK);
            float nm = __uint_as_float(ev & WMASK);
            uint4 xs = x4[(size_t)sx * 16 + colh];
            accA[0] = fmaf(nm, __uint_as_float(xs.x << 16), accA[0]);
            accA[1] = fmaf(nm, __uint_as_float(xs.x & 0xffff0000u), accA[1]);
            accA[2] = fmaf(nm, __uint_as_float(xs.y << 16), accA[2]);
            accA[3] = fmaf(nm, __uint_as_float(xs.y & 0xffff0000u), accA[3]);
            accA[4] = fmaf(nm, __uint_as_float(xs.z << 16), accA[4]);
            accA[5] = fmaf(nm, __uint_as_float(xs.z & 0xffff0000u), accA[5]);
            accA[6] = fmaf(nm, __uint_as_float(xs.w << 16), accA[6]);
            accA[7] = fmaf(nm, __uint_as_float(xs.w & 0xffff0000u), accA[7]);
        }
    }
    for (int base = oM; base < oB; base += 64) {
        uint32_t pc = pB;
        int en = base + 64 + lane;
        pB = (en < oB) ? packed[en] : 0u;
#pragma unroll
        for (int i = 0; i < 64; i += 4) {
            uint32_t ev = (uint32_t)__shfl((int)pc, i + g);
            int sx = (int)(ev & SMASK);
            float nm = __uint_as_float(ev & WMASK);
            uint4 xs = x4[(size_t)sx * 16 + colh];
            accB[0] = fmaf(nm, __uint_as_float(xs.x << 16), accB[0]);
            accB[1] = fmaf(nm, __uint_as_float(xs.x & 0xffff0000u), accB[1]);
            accB[2] = fmaf(nm, __uint_as_float(xs.y << 16), accB[2]);
            accB[3] = fmaf(nm, __uint_as_float(xs.y & 0xffff0000u), accB[3]);
            accB[4] = fmaf(nm, __uint_as_float(xs.z << 16), accB[4]);
            accB[5] = fmaf(nm, __uint_as_float(xs.z & 0xffff0000u), accB[5]);
            accB[6] = fmaf(nm, __uint_as_float(xs.w << 16), accB[6]);
            accB[7] = fmaf(nm, __uint_as_float(xs.w & 0xffff0000u), accB[7]);
        }
    }
#pragma unroll
    for (int off = 16; off <= 32; off <<= 1)
#pragma unroll
        for (int k = 0; k < 8; k++) {
            accA[k] += __shfl_xor(accA[k], off);
            accB[k] += __shfl_xor(accB[k], off);
        }
    int who = lane >> 4;                // 0 -> node A, 1 -> node B
    if (who < 2) {
        int dd = d0 + who;
        float dv = dinv[dd];
        uint4 sv = x4[(size_t)dd * 16 + colh];   // self row (already dinv[d]-scaled)
        float o[8];
#pragma unroll
        for (int k = 0; k < 8; k++) o[k] = (who == 0) ? accA[k] : accB[k];
        o[0] = (o[0] + __uint_as_float(sv.x << 16)) * dv;
        o[1] = (o[1] + __uint_as_float(sv.x & 0xffff0000u)) * dv;
        o[2] = (o[2] + __uint_as_float(sv.y << 16)) * dv;
        o[3] = (o[3] + __uint_as_float(sv.y & 0xffff0000u)) * dv;
        o[4] = (o[4] + __uint_as_float(sv.z << 16)) * dv;
        o[5] = (o[5] + __uint_as_float(sv.z & 0xffff0000u)) * dv;
        o[6] = (o[6] + __uint_as_float(sv.w << 16)) * dv;
        o[7] = (o[7] + __uint_as_float(sv.w & 0xffff0000u)) * dv;
        uint4 r;
        r.x = f2bf(o[0]) | (f2bf(o[1]) << 16);
        r.y = f2bf(o[2]) | (f2bf(o[3]) << 16);
        r.z = f2bf(o[4]) | (f2bf(o[5]) << 16);
        r.w = f2bf(o[6]) | (f2bf(o[7]) << 16);
        ls[(wave * 2 + who) * 16 + colh] = r;    // [node][b] tile in LDS
    }
    __syncthreads();
    int t = threadIdx.x;
    if (t < 128) {                      // one 16B hB row-chunk per thread
        const uint16_t* l16 = (const uint16_t*)ls;
        uint16_t v0 = l16[0 * 128 + t], v1 = l16[1 * 128 + t];
        uint16_t v2 = l16[2 * 128 + t], v3 = l16[3 * 128 + t];
        uint16_t v4 = l16[4 * 128 + t], v5 = l16[5 * 128 + t];
        uint16_t v6 = l16[6 * 128 + t], v7 = l16[7 * 128 + t];
        uint4 r;
        r.x = (uint32_t)v0 | ((uint32_t)v1 << 16);
        r.y = (uint32_t)v2 | ((uint32_t)v3 << 16);
        r.z = (uint32_t)v4 | ((uint32_t)v5 << 16);
        r.w = (uint32_t)v6 | ((uint32_t)v7 << 16);
        *(uint4*)&hB[(size_t)t * N_DIM + blockIdx.x * 8] = r;
    }
}

// ---------- GEMM1 (MFMA bf16, error-compensated W) -> part[kc][b][j] ----------
__global__ void __launch_bounds__(256) k_gemm1(const float* __restrict__ W1,
                                               const uint16_t* __restrict__ hB,
                                               float* __restrict__ part) {
    int kc = blockIdx.x;               // 0..SPLITK-1
    int mt = blockIdx.y;               // 0..7
    int t = threadIdx.x, w = t >> 6, l = t & 63;
    int lr = l & 15;
    int lk = (l >> 4) * 8;
    int row = mt * 64 + w * 16 + lr;   // W1 row for A-frag
    int k0 = kc * KC;
    f32x4 acc[8] = {};
    const float* wbase = W1 + (size_t)row * N_DIM + k0 + lk;
    const uint16_t* hbase = hB + k0 + lk;
#pragma unroll 2
    for (int ks = 0; ks < KC; ks += 32) {
        float4 wa = *(const float4*)(wbase + ks);
        float4 wb = *(const float4*)(wbase + ks + 4);
        short8 bf[8];
#pragma unroll
        for (int c = 0; c < 8; c++)
            bf[c] = *(const short8*)(hbase + (size_t)(c * 16 + lr) * N_DIM + ks);
        float wv0 = wa.x, wv1 = wa.y, wv2 = wa.z, wv3 = wa.w;
        float wv4 = wb.x, wv5 = wb.y, wv6 = wb.z, wv7 = wb.w;
        short8 ahi, alo;
        uint32_t h0;
        h0 = f2bf(wv0); ahi[0] = (short)h0; alo[0] = (short)f2bf(wv0 - __uint_as_float(h0 << 16));
        h0 = f2bf(wv1); ahi[1] = (short)h0; alo[1] = (short)f2bf(wv1 - __uint_as_float(h0 << 16));
        h0 = f2bf(wv2); ahi[2] = (short)h0; alo[2] = (short)f2bf(wv2 - __uint_as_float(h0 << 16));
        h0 = f2bf(wv3); ahi[3] = (short)h0; alo[3] = (short)f2bf(wv3 - __uint_as_float(h0 << 16));
        h0 = f2bf(wv4); ahi[4] = (short)h0; alo[4] = (short)f2bf(wv4 - __uint_as_float(h0 << 16));
        h0 = f2bf(wv5); ahi[5] = (short)h0; alo[5] = (short)f2bf(wv5 - __uint_as_float(h0 << 16));
        h0 = f2bf(wv6); ahi[6] = (short)h0; alo[6] = (short)f2bf(wv6 - __uint_as_float(h0 << 16));
        h0 = f2bf(wv7); ahi[7] = (short)h0; alo[7] = (short)f2bf(wv7 - __uint_as_float(h0 << 16));
#pragma unroll
        for (int c = 0; c < 8; c++) {
            acc[c] = __builtin_amdgcn_mfma_f32_16x16x32_bf16(ahi, bf[c], acc[c], 0, 0, 0);
            acc[c] = __builtin_amdgcn_mfma_f32_16x16x32_bf16(alo, bf[c], acc[c], 0, 0, 0);
        }
    }
    float* pbase = part + (size_t)kc * (H_DIM * B_DIM);
    int j0 = mt * 64 + w * 16 + (l >> 4) * 4;
#pragma unroll
    for (int c = 0; c < 8; c++) {
        int b = c * 16 + lr;
        *(f32x4*)&pbase[(size_t)b * H_DIM + j0] = acc[c];
    }
}

// ---------- fused reduce + GEMM2 + GEMM3: per-batch block ----------
__global__ void __launch_bounds__(1024) k_tail123(const float* __restrict__ part,
                                                  const float* __restrict__ b1,
                                                  const float* __restrict__ W2,
                                                  const float* __restrict__ b2,
                                                  const float* __restrict__ Wfc,
                                                  const float* __restrict__ bfc,
                                                  float* __restrict__ out) {
    __shared__ float h1s[H_DIM];
    __shared__ float h2s[H_DIM];
    int b = blockIdx.x;                 // 0..127
    int t = threadIdx.x;
    {   // Phase R: split-K reduction
        int j = t & 511, half = t >> 9;
        const float* pb = part + (size_t)b * H_DIM + j
                        + (size_t)half * (SPLITK / 2) * (H_DIM * B_DIM);
        float acc = 0.f;
#pragma unroll
        for (int c = 0; c < SPLITK / 2; c++)
            acc += pb[(size_t)c * (H_DIM * B_DIM)];
        if (half == 0) h1s[j] = acc;
        __syncthreads();
        if (half == 1) h1s[j] = fmaxf(h1s[j] + acc + b1[j], 0.f);
        __syncthreads();
    }
    int w = t >> 6;                     // 0..15
    int l = t & 63;
    float hv[8];
#pragma unroll
    for (int k = 0; k < 8; k++) hv[k] = h1s[k * 64 + l];
#pragma unroll
    for (int it = 0; it < 4; it++) {
        int j0 = w * 32 + it * 8;
        float outv = 0.f;
#pragma unroll
        for (int jj = 0; jj < 8; jj++) {
            const float* wrow = W2 + (size_t)(j0 + jj) * H_DIM;
            float a = 0.f;
#pragma unroll
            for (int k = 0; k < 8; k++) a = fmaf(wrow[k * 64 + l], hv[k], a);
#pragma unroll
            for (int o = 1; o < 64; o <<= 1) a += __shfl_xor(a, o);
            if (l == jj) outv = a;
        }
        if (l < 8) h2s[j0 + l] = fmaxf(outv + b2[j0 + l], 0.f);
    }
    __syncthreads();
    if (w == 0) {
        float hv2[8];
#pragma unroll
        for (int k = 0; k < 8; k++) hv2[k] = h2s[k * 64 + l];
        float outv = 0.f;
#pragma unroll
        for (int c = 0; c < C_DIM; c++) {
            const float* wrow = Wfc + (size_t)c * H_DIM;
            float a = 0.f;
#pragma unroll
            for (int k = 0; k < 8; k++) a = fmaf(wrow[k * 64 + l], hv2[k], a);
#pragma unroll
            for (int o = 1; o < 64; o <<= 1) a += __shfl_xor(a, o);
            if (l == c) outv = a;
        }
        if (l < C_DIM) out[b * C_DIM + l] = outv + bfc[l];
    }
}

extern "C" void kernel_launch(void* const* d_in, const int* in_sizes, int n_in,
                              void* d_out, int out_size, void* d_ws, size_t ws_size,
                              hipStream_t stream) {
    const float* x   = (const float*)d_in[0];
    const int*   ei  = (const int*)d_in[1];
    const float* ew  = (const float*)d_in[2];
    const float* W1  = (const float*)d_in[3];
    const float* b1  = (const float*)d_in[4];
    const float* W2  = (const float*)d_in[5];
    const float* b2  = (const float*)d_in[6];
    const float* Wfc = (const float*)d_in[7];
    const float* bfc = (const float*)d_in[8];
    float* out = (float*)d_out;

    const int* src = ei;
    const int* dst = ei + E_DIM;

    char* ws = (char*)d_ws;
    size_t off = 0;
    auto alloc = [&](size_t bytes) -> void* {
        void* p = ws + off;
        off = (off + bytes + 255) & ~(size_t)255;
        return p;
    };
    uint16_t* xTh   = (uint16_t*)alloc((size_t)N_DIM * B_DIM * 2);     // 4 MB bf16 [n][b] (scaled)
    uint32_t* packed = (uint32_t*)alloc((size_t)E_DIM * 4);            // 4 MB encoded edges
    // scratch union (lifetimes disjoint, stream-ordered):
    //   [hist1..place2] : slab8 4 MB + grp8 128 KB
    //   [gemm1..tail123]: part 16 MB
    size_t sort_bytes = (size_t)NWG * NWORD8 * 4 + (size_t)NGRP * NWORD8 * 4;
    size_t part_bytes = (size_t)SPLITK * H_DIM * B_DIM * 4;
    char* scratch = (char*)alloc(sort_bytes > part_bytes ? sort_bytes : part_bytes);
    int*   offs   = (int*)  alloc((size_t)(N_DIM + 1) * 4);
    float* dinv   = (float*)alloc((size_t)N_DIM * 4);
    uint16_t* hB  = (uint16_t*)alloc((size_t)B_DIM * N_DIM * 2);       // 4 MB bf16 [b][n]
    uint32_t* slab = (uint32_t*)scratch;
    uint32_t* grp  = (uint32_t*)(scratch + (size_t)NWG * NWORD8 * 4);
    float* part    = (float*)scratch;      // alias: live only gemm1..tail123
    if (off > ws_size) return;

    k_hist1<<<NWG, 256, 0, stream>>>(dst, slab);
    k_scanA8<<<NWG, 128, 0, stream>>>(slab, grp);
    k_scanBC8<<<1, 1024, 0, stream>>>(grp, offs);
    k_place2<<<NWG, 256, 0, stream>>>(src, dst, ew, slab, grp, offs, packed);
    k_degscale<<<N_DIM / 16, 256, 0, stream>>>(offs, packed, x, dinv, xTh);
    k_diffuse<<<N_DIM / 8, 256, 0, stream>>>(xTh, offs, packed, dinv, hB);
    k_gemm1<<<dim3(SPLITK, H_DIM / 64), 256, 0, stream>>>(W1, hB, part);
    k_tail123<<<B_DIM, 1024, 0, stream>>>(part, b1, W2, b2, Wfc, bfc, out);
}